// Round 1
// baseline (388.870 us; speedup 1.0000x reference)
//
#include <hip/hip_runtime.h>
#include <hip/hip_cooperative_groups.h>
#include <math.h>

namespace cg = cooperative_groups;

// Problem dims
#define B_   512
#define F_   1024
#define H1_  512
#define H2_  256
#define OUT_ 128
#define KD_  5
#define NT_  640
#define ZK_  384   // H2_ + OUT_

typedef short bf16x8 __attribute__((ext_vector_type(8)));
typedef float f32x16 __attribute__((ext_vector_type(16)));

__device__ __forceinline__ float lrelu(float v) { return v >= 0.f ? v : 0.2f * v; }

// fp32 -> bf16 round-to-nearest-even
__device__ __forceinline__ unsigned f2bf(float f) {
    unsigned u = __float_as_uint(f);
    return (u + 0x7fffu + ((u >> 16) & 1u)) >> 16;
}
__device__ __forceinline__ unsigned pack2bf(float a, float b) {
    return f2bf(a) | (f2bf(b) << 16);
}

// ---------------------------------------------------------------------------
// MFMA fragment loaders (verified layouts, unchanged from previous session)
// ---------------------------------------------------------------------------
__device__ __forceinline__ bf16x8 frag_bf16row(const unsigned short* p, int idx, int ld, int k) {
    return *(const bf16x8*)(p + (size_t)idx * ld + k);
}
__device__ __forceinline__ bf16x8 frag_f32row(const float* p, int idx, int ld, int k) {
    const float4 a = *(const float4*)(p + (size_t)idx * ld + k);
    const float4 b = *(const float4*)(p + (size_t)idx * ld + k + 4);
    union { unsigned u[4]; bf16x8 v; } cv;
    cv.u[0] = pack2bf(a.x, a.y); cv.u[1] = pack2bf(a.z, a.w);
    cv.u[2] = pack2bf(b.x, b.y); cv.u[3] = pack2bf(b.z, b.w);
    return cv.v;
}
// column gather from fp32 [K][ld] matrix: element j = p[(k+j)*ld + idx]
__device__ __forceinline__ bf16x8 frag_f32col(const float* p, int idx, int ld, int k) {
    union { unsigned u[4]; bf16x8 v; } cv;
    #pragma unroll
    for (int jj = 0; jj < 4; ++jj)
        cv.u[jj] = pack2bf(p[(size_t)(k + 2 * jj) * ld + idx],
                           p[(size_t)(k + 2 * jj + 1) * ld + idx]);
    return cv.v;
}

#define M_BF16ROW 0
#define M_F32ROW  1
#define M_F32COL  2

// ---------------------------------------------------------------------------
// One 32x32 output tile, K split across 8 waves (barrier-free K-loop,
// single LDS reduction). Device-function version for the mega-kernel.
// Trailing __syncthreads protects LDS reuse by the caller.
// ---------------------------------------------------------------------------
template<int KSLICE, int AMODE, int BMODE, bool RELU, bool HAS_BIAS, bool BF16_OUT>
__device__ __forceinline__
void gemm_tile(float* Red,
               const void* __restrict__ Ap, const void* __restrict__ Bp,
               const float* __restrict__ bias, void* __restrict__ Cout,
               int N, int LDA, int LDB, int m0, int n0, int tid)
{
    const int wav  = tid >> 6;
    const int lane = tid & 63;
    const int half = lane >> 5;
    const int mn   = lane & 31;

    f32x16 acc;
    #pragma unroll
    for (int i = 0; i < 16; ++i) acc[i] = 0.f;

    #pragma unroll
    for (int s = 0; s < KSLICE / 16; ++s) {
        const int k = wav * KSLICE + 16 * s + 8 * half;
        bf16x8 af, bf;
        if (AMODE == M_BF16ROW)      af = frag_bf16row((const unsigned short*)Ap, m0 + mn, LDA, k);
        else if (AMODE == M_F32ROW)  af = frag_f32row((const float*)Ap, m0 + mn, LDA, k);
        else                         af = frag_f32col((const float*)Ap, m0 + mn, LDA, k);
        if (BMODE == M_BF16ROW)      bf = frag_bf16row((const unsigned short*)Bp, n0 + mn, LDB, k);
        else                         bf = frag_f32col((const float*)Bp, n0 + mn, LDB, k);
        acc = __builtin_amdgcn_mfma_f32_32x32x16_bf16(af, bf, acc, 0, 0, 0);
    }

    // C/D layout (verified): col = lane&31, row = (reg&3) + 8*(reg>>2) + 4*(lane>>5)
    #pragma unroll
    for (int r = 0; r < 16; ++r) {
        const int row = (r & 3) + 8 * (r >> 2) + 4 * half;
        Red[wav * 1024 + row * 32 + mn] = acc[r];
    }
    __syncthreads();

    if (tid < 256) {
        const int e0 = tid * 4, row = e0 >> 5, col = e0 & 31;
        float v[4];
        #pragma unroll
        for (int q = 0; q < 4; ++q) {
            float u = 0.f;
            #pragma unroll
            for (int w = 0; w < 8; ++w) u += Red[w * 1024 + e0 + q];
            if (HAS_BIAS) u += bias[n0 + col + q];
            if (RELU) u = lrelu(u);
            v[q] = u;
        }
        if (BF16_OUT) {
            uint2 o;
            o.x = pack2bf(v[0], v[1]); o.y = pack2bf(v[2], v[3]);
            *(uint2*)((unsigned short*)Cout + (size_t)(m0 + row) * N + n0 + col) = o;
        } else {
            *(float4*)((float*)Cout + (size_t)(m0 + row) * N + n0 + col) =
                make_float4(v[0], v[1], v[2], v[3]);
        }
    }
    __syncthreads();
}

// ---------------------------------------------------------------------------
// Minibatch discrimination, 512-thread form: block b -> (o = b>>1, jh = b&1).
// thread -> (j = jh*256 + (tid&255), i-half = tid>>8). Each thread sums 256
// exp(-L1) terms; the two i-half partials combine in LDS; obF is the FULL
// sum in [o][j] layout (coalesced writes, and Ph5 reads it as frag_f32col).
// ---------------------------------------------------------------------------
__device__ __forceinline__
void disc_phase(float* S, const float* __restrict__ Mt, float* __restrict__ obF,
                int b, int tid)
{
    float* L = S;          // [512][8] fp32 staging of Mt rows o*5..o*5+4
    float* P = S + 4096;   // [256] i-half partial
    const int o  = b >> 1;
    const int jh = b & 1;
    const int t  = tid & 255;
    const int ih = tid >> 8;
    const float* base = Mt + (size_t)o * (KD_ * 512);

    #pragma unroll
    for (int k = 0; k < KD_; ++k)
        L[tid * 8 + k] = base[k * 512 + tid];

    const int j = jh * 256 + t;
    const float mj0 = base[0 * 512 + j], mj1 = base[1 * 512 + j],
                mj2 = base[2 * 512 + j], mj3 = base[3 * 512 + j],
                mj4 = base[4 * 512 + j];
    __syncthreads();

    const int i0 = ih * 256;
    float acc0 = 0.f, acc1 = 0.f;
    #pragma unroll 4
    for (int i = 0; i < 256; i += 2) {
        {
            const float4 a = *(const float4*)&L[(i0 + i) * 8];
            const float n = fabsf(a.x - mj0) + fabsf(a.y - mj1) + fabsf(a.z - mj2)
                          + fabsf(a.w - mj3) + fabsf(L[(i0 + i) * 8 + 4] - mj4);
            acc0 += __expf(-n);
        }
        {
            const float4 a = *(const float4*)&L[(i0 + i + 1) * 8];
            const float n = fabsf(a.x - mj0) + fabsf(a.y - mj1) + fabsf(a.z - mj2)
                          + fabsf(a.w - mj3) + fabsf(L[(i0 + i + 1) * 8 + 4] - mj4);
            acc1 += __expf(-n);
        }
    }
    if (ih == 0) P[t] = acc0 + acc1;
    __syncthreads();
    if (ih == 1) obF[(size_t)o * B_ + j] = P[t] + acc0 + acc1 - 1.0f;  // -1: self term
    __syncthreads();
}

// ---------------------------------------------------------------------------
// Final GEMM3 + dot, 512-thread form: wave w -> col-tile n0=(w&3)*32,
// K-half kh=w>>2 (K=384 split 2-way). Partials summed in LDS, then
// bias+lrelu inside the rotated W4 dot.
// ---------------------------------------------------------------------------
__device__ __forceinline__
void final_phase(float* Red, const unsigned short* __restrict__ h2b,
                 const float* __restrict__ obF,
                 const float* __restrict__ W3, const float* __restrict__ b3,
                 const float* __restrict__ W4, const float* __restrict__ b4,
                 float* __restrict__ out, int m0, int tid)
{
    const int w    = tid >> 6;
    const int lane = tid & 63;
    const int half = lane >> 5;
    const int mn   = lane & 31;
    const int n0   = (w & 3) * 32;
    const int kh   = w >> 2;

    f32x16 acc;
    #pragma unroll
    for (int i = 0; i < 16; ++i) acc[i] = 0.f;

    #pragma unroll
    for (int s = 0; s < 12; ++s) {
        const int k = kh * 192 + 16 * s + 8 * half;
        const int idx = m0 + mn;
        bf16x8 af;
        if (k < H2_) af = frag_bf16row(h2b, idx, H2_, k);
        else         af = frag_f32col(obF, idx, B_, k - H2_);
        const bf16x8 bf = frag_f32col(W3, n0 + mn, OUT_, k);
        acc = __builtin_amdgcn_mfma_f32_32x32x16_bf16(af, bf, acc, 0, 0, 0);
    }

    #pragma unroll
    for (int r = 0; r < 16; ++r) {
        const int row = (r & 3) + 8 * (r >> 2) + 4 * half;
        Red[kh * 4096 + row * 128 + n0 + mn] = acc[r];
    }
    __syncthreads();

    if (tid < 128) {
        const int row = tid >> 2, q = tid & 3;
        float a = 0.f;
        #pragma unroll
        for (int cc0 = 0; cc0 < 32; ++cc0) {
            const int cc = (cc0 + tid) & 31;       // rotation: 2-way LDS aliasing (free)
            const int c = q * 32 + cc;
            const float u = lrelu(Red[row * 128 + c] + Red[4096 + row * 128 + c] + b3[c]);
            a += u * W4[c];
        }
        a += __shfl_down(a, 2, 4);
        a += __shfl_down(a, 1, 4);
        if (q == 0) out[m0 + row] = a + b4[0];
    }
}

// ---------------------------------------------------------------------------
// Mega-kernel: 256 blocks x 512 threads, cooperative launch, 4 grid syncs
// replace 4 kernel-launch boundaries.
// ---------------------------------------------------------------------------
__global__ __launch_bounds__(512)
void mega(const float* __restrict__ x,  const float* __restrict__ W1, const float* __restrict__ b1,
          const float* __restrict__ W2, const float* __restrict__ b2,
          const float* __restrict__ T,
          const float* __restrict__ W3, const float* __restrict__ b3,
          const float* __restrict__ W4, const float* __restrict__ b4,
          float* __restrict__ Mt, float* __restrict__ obF,
          unsigned short* __restrict__ h1b, unsigned short* __restrict__ h2b,
          float* __restrict__ out)
{
    __shared__ float S[8192];   // 32 KiB, reused by every phase
    cg::grid_group grid = cg::this_grid();
    const int b   = blockIdx.x;
    const int tid = threadIdx.x;

    // Ph1: h1 = lrelu(x @ W1 + b1) -> bf16 [512][512]; 256 tiles (16x16)
    gemm_tile<128, M_F32ROW, M_F32COL, true, true, true>(
        S, x, W1, b1, h1b, H1_, F_, H1_, (b >> 4) * 32, (b & 15) * 32, tid);
    __threadfence(); grid.sync();

    // Ph2: h2 = lrelu(h1 @ W2 + b2) -> bf16 [512][256]; 128 tiles
    if (b < 128)
        gemm_tile<64, M_BF16ROW, M_F32COL, true, true, true>(
            S, h1b, W2, b2, h2b, H2_, H1_, H2_, (b >> 3) * 32, (b & 7) * 32, tid);
    __threadfence(); grid.sync();

    // Ph3: Mt = (h2 @ T)^T -> fp32 [640][512]; 320 tiles grid-strided
    for (int t = b; t < 320; t += 256)
        gemm_tile<32, M_F32COL, M_BF16ROW, false, false, false>(
            S, T, h2b, nullptr, Mt, B_, NT_, H2_, (t / 16) * 32, (t % 16) * 32, tid);
    __threadfence(); grid.sync();

    // Ph4: minibatch discrimination -> obF fp32 [128][512] (full sum)
    disc_phase(S, Mt, obF, b, tid);
    __threadfence(); grid.sync();

    // Ph5: out = lrelu(concat([h2, ob]) @ W3 + b3) @ W4 + b4; 16 row strips
    if (b < 16)
        final_phase(S, h2b, obF, W3, b3, W4, b4, out, b * 32, tid);
}

extern "C" void kernel_launch(void* const* d_in, const int* in_sizes, int n_in,
                              void* d_out, int out_size, void* d_ws, size_t ws_size,
                              hipStream_t stream) {
    const float* x  = (const float*)d_in[0];   // (512, 1024)
    const float* W1 = (const float*)d_in[1];   // (1024, 512)
    const float* b1 = (const float*)d_in[2];   // (512,)
    const float* W2 = (const float*)d_in[3];   // (512, 256)
    const float* b2 = (const float*)d_in[4];   // (256,)
    const float* T  = (const float*)d_in[5];   // (256, 640) flat
    const float* W3 = (const float*)d_in[6];   // (384, 128)
    const float* b3 = (const float*)d_in[7];   // (128,)
    const float* W4 = (const float*)d_in[8];   // (128, 1)
    const float* b4 = (const float*)d_in[9];   // (1,)
    float* out = (float*)d_out;                // (512,)

    char* ws = (char*)d_ws;
    float*          Mt  = (float*)(ws + 0);                  // 640*512*4   = 1310720
    float*          obF = (float*)(ws + 1310720);            // 128*512*4   =  262144
    unsigned short* h1b = (unsigned short*)(ws + 1572864);   // 512*512*2   =  524288
    unsigned short* h2b = (unsigned short*)(ws + 2097152);   // 512*256*2   =  262144
    // total 2,359,296 bytes

    void* args[] = { (void*)&x,  (void*)&W1, (void*)&b1, (void*)&W2, (void*)&b2,
                     (void*)&T,  (void*)&W3, (void*)&b3, (void*)&W4, (void*)&b4,
                     (void*)&Mt, (void*)&obF, (void*)&h1b, (void*)&h2b, (void*)&out };
    hipLaunchCooperativeKernel((const void*)mega, dim3(256), dim3(512), args, 0, stream);
}

// Round 4
// 117.534 us; speedup vs baseline: 3.3086x; 3.3086x over previous
//
#include <hip/hip_runtime.h>
#include <math.h>

// Problem dims
#define B_   512
#define F_   1024
#define H1_  512
#define H2_  256
#define OUT_ 128
#define KD_  5
#define NT_  640
#define ZK_  384   // H2_ + OUT_

typedef short bf16x8 __attribute__((ext_vector_type(8)));
typedef float f32x16 __attribute__((ext_vector_type(16)));

__device__ __forceinline__ float lrelu(float v) { return v >= 0.f ? v : 0.2f * v; }

// fp32 -> bf16 round-to-nearest-even
__device__ __forceinline__ unsigned f2bf(float f) {
    unsigned u = __float_as_uint(f);
    return (u + 0x7fffu + ((u >> 16) & 1u)) >> 16;
}
__device__ __forceinline__ unsigned pack2bf(float a, float b) {
    return f2bf(a) | (f2bf(b) << 16);
}

// ---------------------------------------------------------------------------
// MFMA fragment loaders (A/B lane layout: idx = lane&31, k = (lane>>5)*8 + j,
// j = 0..7 contiguous). Verified in the previous session (absmax 5.9e-3).
// ---------------------------------------------------------------------------
__device__ __forceinline__ bf16x8 frag_bf16row(const unsigned short* p, int idx, int ld, int k) {
    return *(const bf16x8*)(p + (size_t)idx * ld + k);
}
__device__ __forceinline__ bf16x8 frag_f32row(const float* p, int idx, int ld, int k) {
    const float4 a = *(const float4*)(p + (size_t)idx * ld + k);
    const float4 b = *(const float4*)(p + (size_t)idx * ld + k + 4);
    union { unsigned u[4]; bf16x8 v; } cv;
    cv.u[0] = pack2bf(a.x, a.y); cv.u[1] = pack2bf(a.z, a.w);
    cv.u[2] = pack2bf(b.x, b.y); cv.u[3] = pack2bf(b.z, b.w);
    return cv.v;
}
// column gather from fp32 [K][ld] matrix: element j = p[(k+j)*ld + idx]
__device__ __forceinline__ bf16x8 frag_f32col(const float* p, int idx, int ld, int k) {
    union { unsigned u[4]; bf16x8 v; } cv;
    #pragma unroll
    for (int jj = 0; jj < 4; ++jj)
        cv.u[jj] = pack2bf(p[(size_t)(k + 2 * jj) * ld + idx],
                           p[(size_t)(k + 2 * jj + 1) * ld + idx]);
    return cv.v;
}
// concat([h2b bf16 (ld 256), obA+obB fp32 (ld 128)]) row, K=384
__device__ __forceinline__ bf16x8 frag_concat(const unsigned short* h2b,
                                              const float* obA, const float* obB,
                                              int idx, int k) {
    if (k < H2_) return frag_bf16row(h2b, idx, H2_, k);
    const float* pa = obA + (size_t)idx * OUT_ + (k - H2_);
    const float* pb = obB + (size_t)idx * OUT_ + (k - H2_);
    union { unsigned u[4]; bf16x8 v; } cv;
    #pragma unroll
    for (int jj = 0; jj < 4; ++jj)
        cv.u[jj] = pack2bf(pa[2 * jj] + pb[2 * jj], pa[2 * jj + 1] + pb[2 * jj + 1]);
    return cv.v;
}

// operand modes
#define M_BF16ROW 0
#define M_F32ROW  1
#define M_F32COL  2

// ---------------------------------------------------------------------------
// Barrier-free MFMA GEMM, one 32x32 tile per block, K split across WAVES
// waves (no barriers/LDS in the K-loop; single LDS reduction + epilogue).
// Byte-identical to the verified round-0 kernel.
// ---------------------------------------------------------------------------
template<int WAVES, int KSLICE, int AMODE, int BMODE,
         bool RELU, bool HAS_BIAS, bool BF16_OUT>
__global__ __launch_bounds__(WAVES * 64)
void gemm_k(const void* __restrict__ Ap, const void* __restrict__ Bp,
            const float* __restrict__ bias, void* __restrict__ Cout,
            int M, int N, int LDA, int LDB)
{
    __shared__ float Red[WAVES * 1024];
    const int tid  = threadIdx.x;
    const int wav  = tid >> 6;
    const int lane = tid & 63;
    const int half = lane >> 5;
    const int mn   = lane & 31;
    const int m0   = blockIdx.y * 32;
    const int n0   = blockIdx.x * 32;

    f32x16 acc;
    #pragma unroll
    for (int i = 0; i < 16; ++i) acc[i] = 0.f;

    #pragma unroll
    for (int s = 0; s < KSLICE / 16; ++s) {
        const int k = wav * KSLICE + 16 * s + 8 * half;
        bf16x8 af, bf;
        if (AMODE == M_BF16ROW)      af = frag_bf16row((const unsigned short*)Ap, m0 + mn, LDA, k);
        else if (AMODE == M_F32ROW)  af = frag_f32row((const float*)Ap, m0 + mn, LDA, k);
        else                         af = frag_f32col((const float*)Ap, m0 + mn, LDA, k);
        if (BMODE == M_BF16ROW)      bf = frag_bf16row((const unsigned short*)Bp, n0 + mn, LDB, k);
        else                         bf = frag_f32col((const float*)Bp, n0 + mn, LDB, k);
        acc = __builtin_amdgcn_mfma_f32_32x32x16_bf16(af, bf, acc, 0, 0, 0);
    }

    // C/D layout (verified): col = lane&31, row = (reg&3) + 8*(reg>>2) + 4*(lane>>5)
    #pragma unroll
    for (int r = 0; r < 16; ++r) {
        const int row = (r & 3) + 8 * (r >> 2) + 4 * half;
        Red[wav * 1024 + row * 32 + mn] = acc[r];
    }
    __syncthreads();

    if (tid < 256) {
        const int e0 = tid * 4, row = e0 >> 5, col = e0 & 31;
        float v[4];
        #pragma unroll
        for (int q = 0; q < 4; ++q) {
            float u = 0.f;
            #pragma unroll
            for (int w = 0; w < WAVES; ++w) u += Red[w * 1024 + e0 + q];
            if (HAS_BIAS) u += bias[n0 + col + q];
            if (RELU) u = lrelu(u);
            v[q] = u;
        }
        if (BF16_OUT) {
            uint2 o;
            o.x = pack2bf(v[0], v[1]); o.y = pack2bf(v[2], v[3]);
            *(uint2*)((unsigned short*)Cout + (size_t)(m0 + row) * N + n0 + col) = o;
        } else {
            *(float4*)((float*)Cout + (size_t)(m0 + row) * N + n0 + col) =
                make_float4(v[0], v[1], v[2], v[3]);
        }
    }
}

// ---------------------------------------------------------------------------
// Fused Mt + minibatch discrimination (v2, cache-busting rename).
// 256 blocks x 512 threads. Block b -> (o = b>>1, ih = b&1).
// Step 1: M-slice M[i][o][kk] = sum_c h2[i][c] * T[c][o*5+kk], i in [0,512),
// kk<5, via MFMA (A = h2b rows; B = zero-padded T column gather, cols 5..31
// zero and unused). Slice -> LDS [512][8].
// Step 2: verified pairwise exp(-L1) loop; thread j = tid, i over the
// block's i-half; obH gets the two i-half partials.
// ---------------------------------------------------------------------------
__global__ __launch_bounds__(512)
void discM2_kernel(const unsigned short* __restrict__ h2b,
                   const float* __restrict__ T,
                   float* __restrict__ obH)
{
    __shared__ float Msl[512 * 8];   // [i][kk], kk padded 5->8 (32B rows)
    const int b    = blockIdx.x;
    const int o    = b >> 1;
    const int ih   = b & 1;
    const int tid  = threadIdx.x;
    const int w    = tid >> 6;
    const int lane = tid & 63;
    const int half = lane >> 5;
    const int mn   = lane & 31;

    // T column base for this (o, lane): column o*5 + mn of the [256][640] T
    const float* Tc = T + (size_t)o * KD_ + mn;
    const bool   tc_ok = (mn < KD_);

    // ---- Step 1: M-slice via MFMA. Wave w owns rows [w*64, w*64+64). ----
    const int m0 = w * 64;
    f32x16 acc0, acc1;
    #pragma unroll
    for (int i = 0; i < 16; ++i) { acc0[i] = 0.f; acc1[i] = 0.f; }

    #pragma unroll 4
    for (int s = 0; s < 16; ++s) {
        const int k = 16 * s + 8 * half;
        union { unsigned u[4]; bf16x8 v; } cv;
        cv.u[0] = 0u; cv.u[1] = 0u; cv.u[2] = 0u; cv.u[3] = 0u;
        if (tc_ok) {
            #pragma unroll
            for (int jj = 0; jj < 4; ++jj)
                cv.u[jj] = pack2bf(Tc[(size_t)(k + 2 * jj) * NT_],
                                   Tc[(size_t)(k + 2 * jj + 1) * NT_]);
        }
        const bf16x8 bfr = cv.v;
        const bf16x8 a0 = frag_bf16row(h2b, m0 + mn, H2_, k);
        const bf16x8 a1 = frag_bf16row(h2b, m0 + 32 + mn, H2_, k);
        acc0 = __builtin_amdgcn_mfma_f32_32x32x16_bf16(a0, bfr, acc0, 0, 0, 0);
        acc1 = __builtin_amdgcn_mfma_f32_32x32x16_bf16(a1, bfr, acc1, 0, 0, 0);
    }
    // C/D layout: col = lane&31 (= kk), row = (r&3) + 8*(r>>2) + 4*half
    #pragma unroll
    for (int r = 0; r < 16; ++r) {
        const int row = (r & 3) + 8 * (r >> 2) + 4 * half;
        if (tc_ok) {
            Msl[(m0 + row) * 8 + mn]      = acc0[r];
            Msl[(m0 + 32 + row) * 8 + mn] = acc1[r];
        }
    }
    __syncthreads();

    // ---- Step 2: pairwise exp(-L1) over the block's i-half ----
    const int j = tid;
    const float mj0 = Msl[j * 8 + 0], mj1 = Msl[j * 8 + 1], mj2 = Msl[j * 8 + 2],
                mj3 = Msl[j * 8 + 3], mj4 = Msl[j * 8 + 4];
    const int i0 = ih * 256;

    float acca = 0.f, accb = 0.f;
    #pragma unroll 4
    for (int i = 0; i < 256; i += 2) {
        {
            const float4 a = *(const float4*)&Msl[(i0 + i) * 8];
            const float n = fabsf(a.x - mj0) + fabsf(a.y - mj1) + fabsf(a.z - mj2)
                          + fabsf(a.w - mj3) + fabsf(Msl[(i0 + i) * 8 + 4] - mj4);
            acca += __expf(-n);
        }
        {
            const float4 a = *(const float4*)&Msl[(i0 + i + 1) * 8];
            const float n = fabsf(a.x - mj0) + fabsf(a.y - mj1) + fabsf(a.z - mj2)
                          + fabsf(a.w - mj3) + fabsf(Msl[(i0 + i + 1) * 8 + 4] - mj4);
            accb += __expf(-n);
        }
    }
    const float self = ((j >> 8) == ih) ? 1.f : 0.f;
    obH[(size_t)ih * B_ * OUT_ + (size_t)j * OUT_ + o] = acca + accb - self;
}

// ---------------------------------------------------------------------------
// Fused GEMM3 + final dot: 16 blocks x 256 threads (verified round-0 code).
// ---------------------------------------------------------------------------
__global__ __launch_bounds__(256)
void gemm3_dot(const unsigned short* __restrict__ h2b,
               const float* __restrict__ obA, const float* __restrict__ obB,
               const float* __restrict__ W3, const float* __restrict__ b3,
               const float* __restrict__ W4, const float* __restrict__ b4,
               float* __restrict__ out)
{
    __shared__ float Red[32 * 128];
    const int tid  = threadIdx.x;
    const int w    = tid >> 6;
    const int lane = tid & 63;
    const int half = lane >> 5;
    const int mn   = lane & 31;
    const int m0   = blockIdx.x * 32;
    const int n0   = w * 32;

    f32x16 acc;
    #pragma unroll
    for (int i = 0; i < 16; ++i) acc[i] = 0.f;

    #pragma unroll
    for (int s = 0; s < ZK_ / 16; ++s) {
        const int k = 16 * s + 8 * half;
        const bf16x8 af = frag_concat(h2b, obA, obB, m0 + mn, k);
        const bf16x8 bfr = frag_f32col(W3, n0 + mn, OUT_, k);
        acc = __builtin_amdgcn_mfma_f32_32x32x16_bf16(af, bfr, acc, 0, 0, 0);
    }

    #pragma unroll
    for (int r = 0; r < 16; ++r) {
        const int row = (r & 3) + 8 * (r >> 2) + 4 * half;
        const int col = n0 + mn;
        Red[row * 128 + col] = lrelu(acc[r] + b3[col]);
    }
    __syncthreads();

    if (tid < 128) {
        const int row = tid >> 2, q = tid & 3;
        float a = 0.f;
        #pragma unroll
        for (int cc0 = 0; cc0 < 32; ++cc0) {
            const int cc = (cc0 + tid) & 31;       // rotation: 2-way LDS aliasing (free)
            a += Red[row * 128 + q * 32 + cc] * W4[q * 32 + cc];
        }
        a += __shfl_down(a, 2, 4);
        a += __shfl_down(a, 1, 4);
        if (q == 0) out[m0 + row] = a + b4[0];
    }
}

extern "C" void kernel_launch(void* const* d_in, const int* in_sizes, int n_in,
                              void* d_out, int out_size, void* d_ws, size_t ws_size,
                              hipStream_t stream) {
    const float* x  = (const float*)d_in[0];   // (512, 1024)
    const float* W1 = (const float*)d_in[1];   // (1024, 512)
    const float* b1 = (const float*)d_in[2];   // (512,)
    const float* W2 = (const float*)d_in[3];   // (512, 256)
    const float* b2 = (const float*)d_in[4];   // (256,)
    const float* T  = (const float*)d_in[5];   // (256, 640) flat
    const float* W3 = (const float*)d_in[6];   // (384, 128)
    const float* b3 = (const float*)d_in[7];   // (128,)
    const float* W4 = (const float*)d_in[8];   // (128, 1)
    const float* b4 = (const float*)d_in[9];   // (1,)
    float* out = (float*)d_out;                // (512,)

    char* ws = (char*)d_ws;
    float*          obH = (float*)(ws + 0);                  // 2*512*128*4 = 524288
    unsigned short* h1b = (unsigned short*)(ws + 524288);    // 512*512*2   = 524288
    unsigned short* h2b = (unsigned short*)(ws + 1048576);   // 512*256*2   = 262144
    // total 1,310,720 bytes

    // 1) h1 = lrelu(x @ W1 + b1)  (512x512, K=1024) -> bf16
    gemm_k<8, 128, M_F32ROW, M_F32COL, true, true, true>
        <<<dim3(H1_ / 32, B_ / 32), 512, 0, stream>>>(
        x, W1, b1, h1b, B_, H1_, F_, H1_);

    // 2) h2 = lrelu(h1 @ W2 + b2) (512x256, K=512) -> bf16
    gemm_k<8, 64, M_BF16ROW, M_F32COL, true, true, true>
        <<<dim3(H2_ / 32, B_ / 32), 512, 0, stream>>>(
        h1b, W2, b2, h2b, B_, H2_, H1_, H2_);

    // 3) fused Mt + minibatch discrimination -> obH (two i-half partials)
    discM2_kernel<<<256, 512, 0, stream>>>(h2b, T, obH);

    // 4) out = (lrelu(concat([h2, ob]) @ W3 + b3)) @ W4 + b4
    gemm3_dot<<<B_ / 32, 256, 0, stream>>>(
        h2b, obH, obH + B_ * OUT_, W3, b3, W4, b4, out);
}

// Round 5
// 115.228 us; speedup vs baseline: 3.3748x; 1.0200x over previous
//
#include <hip/hip_runtime.h>
#include <math.h>

// Problem dims
#define B_   512
#define F_   1024
#define H1_  512
#define H2_  256
#define OUT_ 128
#define KD_  5
#define NT_  640
#define ZK_  384   // H2_ + OUT_

typedef short bf16x8 __attribute__((ext_vector_type(8)));
typedef float f32x16 __attribute__((ext_vector_type(16)));

__device__ __forceinline__ float lrelu(float v) { return v >= 0.f ? v : 0.2f * v; }

// fp32 -> bf16 round-to-nearest-even
__device__ __forceinline__ unsigned f2bf(float f) {
    unsigned u = __float_as_uint(f);
    return (u + 0x7fffu + ((u >> 16) & 1u)) >> 16;
}
__device__ __forceinline__ unsigned pack2bf(float a, float b) {
    return f2bf(a) | (f2bf(b) << 16);
}

// ---------------------------------------------------------------------------
// MFMA fragment loaders (A/B lane layout: idx = lane&31, k = (lane>>5)*8 + j,
// j = 0..7 contiguous). Verified (absmax 5.9e-3).
// ---------------------------------------------------------------------------
__device__ __forceinline__ bf16x8 frag_bf16row(const unsigned short* p, int idx, int ld, int k) {
    return *(const bf16x8*)(p + (size_t)idx * ld + k);
}
// concat([h2b bf16 (ld 256), obA+obB fp32 (ld 128)]) row, K=384
__device__ __forceinline__ bf16x8 frag_concat(const unsigned short* h2b,
                                              const float* obA, const float* obB,
                                              int idx, int k) {
    if (k < H2_) return frag_bf16row(h2b, idx, H2_, k);
    const float* pa = obA + (size_t)idx * OUT_ + (k - H2_);
    const float* pb = obB + (size_t)idx * OUT_ + (k - H2_);
    union { unsigned u[4]; bf16x8 v; } cv;
    #pragma unroll
    for (int jj = 0; jj < 4; ++jj)
        cv.u[jj] = pack2bf(pa[2 * jj] + pb[2 * jj], pa[2 * jj + 1] + pb[2 * jj + 1]);
    return cv.v;
}

// ---------------------------------------------------------------------------
// Prep: one dispatch, 1104 blocks x 256 threads.
//  blocks [0,512)    : W1 [1024][512] fp32 -> W1t [512][1024] bf16 (transpose)
//  blocks [512,640)  : W2 [512][256]  fp32 -> W2t [256][512]  bf16
//  blocks [640,800)  : T  [256][640]  fp32 -> Tt  [640][256]  bf16
//  blocks [800,848)  : W3 [384][128]  fp32 -> W3t [128][384]  bf16
//  blocks [848,1104) : x  [512][1024] fp32 -> xb bf16 (convert, no transpose)
// Transpose via 32x32 LDS tile (+1 pad col): both global read and write are
// coalesced; bf16 RNE rounding identical to the old per-fragment pack.
// ---------------------------------------------------------------------------
__global__ __launch_bounds__(256)
void prep_kernel(const float* __restrict__ x,  const float* __restrict__ W1,
                 const float* __restrict__ W2, const float* __restrict__ T,
                 const float* __restrict__ W3,
                 unsigned short* __restrict__ xb,  unsigned short* __restrict__ W1t,
                 unsigned short* __restrict__ W2t, unsigned short* __restrict__ Tt,
                 unsigned short* __restrict__ W3t)
{
    __shared__ float L[32][33];
    const int b = blockIdx.x, tid = threadIdx.x;
    if (b < 848) {
        const float* in; unsigned short* outp; int R, C, tile;
        if (b < 512)      { in = W1; outp = W1t; R = 1024; C = 512; tile = b; }
        else if (b < 640) { in = W2; outp = W2t; R = 512;  C = 256; tile = b - 512; }
        else if (b < 800) { in = T;  outp = Tt;  R = 256;  C = 640; tile = b - 640; }
        else              { in = W3; outp = W3t; R = 384;  C = 128; tile = b - 800; }
        const int nc = C >> 5;
        const int r0 = (tile / nc) * 32, c0 = (tile % nc) * 32;
        const int lr = tid >> 3, lc = (tid & 7) * 4;
        const float4 v = *(const float4*)(in + (size_t)(r0 + lr) * C + c0 + lc);
        L[lr][lc + 0] = v.x; L[lr][lc + 1] = v.y;
        L[lr][lc + 2] = v.z; L[lr][lc + 3] = v.w;
        __syncthreads();
        // out[c0+orow][r0+ocol+j] = in[r0+ocol+j][c0+orow] = L[ocol+j][orow]
        const int orow = tid >> 3, ocol = (tid & 7) * 4;
        uint2 o;
        o.x = pack2bf(L[ocol + 0][orow], L[ocol + 1][orow]);
        o.y = pack2bf(L[ocol + 2][orow], L[ocol + 3][orow]);
        *(uint2*)(outp + (size_t)(c0 + orow) * R + r0 + ocol) = o;
    } else {
        const int e = (b - 848) * 2048 + tid * 8;
        const float4 a = *(const float4*)(x + e);
        const float4 c = *(const float4*)(x + e + 4);
        uint4 o;
        o.x = pack2bf(a.x, a.y); o.y = pack2bf(a.z, a.w);
        o.z = pack2bf(c.x, c.y); o.w = pack2bf(c.z, c.w);
        *(uint4*)(xb + e) = o;
    }
}

// ---------------------------------------------------------------------------
// Barrier-free MFMA GEMM, one 32x32 tile per block, K split across WAVES
// waves (no barriers/LDS in the K-loop; single LDS reduction + epilogue).
// Both operands are now bf16 row-major (single b128 load per fragment).
// ---------------------------------------------------------------------------
template<int WAVES, int KSLICE, bool RELU, bool HAS_BIAS, bool BF16_OUT>
__global__ __launch_bounds__(WAVES * 64)
void gemm_k(const unsigned short* __restrict__ Ap, const unsigned short* __restrict__ Bp,
            const float* __restrict__ bias, void* __restrict__ Cout,
            int N, int LDA, int LDB)
{
    __shared__ float Red[WAVES * 1024];
    const int tid  = threadIdx.x;
    const int wav  = tid >> 6;
    const int lane = tid & 63;
    const int half = lane >> 5;
    const int mn   = lane & 31;
    const int m0   = blockIdx.y * 32;
    const int n0   = blockIdx.x * 32;

    f32x16 acc;
    #pragma unroll
    for (int i = 0; i < 16; ++i) acc[i] = 0.f;

    #pragma unroll
    for (int s = 0; s < KSLICE / 16; ++s) {
        const int k = wav * KSLICE + 16 * s + 8 * half;
        const bf16x8 af = frag_bf16row(Ap, m0 + mn, LDA, k);
        const bf16x8 bf = frag_bf16row(Bp, n0 + mn, LDB, k);
        acc = __builtin_amdgcn_mfma_f32_32x32x16_bf16(af, bf, acc, 0, 0, 0);
    }

    // C/D layout (verified): col = lane&31, row = (reg&3) + 8*(reg>>2) + 4*(lane>>5)
    #pragma unroll
    for (int r = 0; r < 16; ++r) {
        const int row = (r & 3) + 8 * (r >> 2) + 4 * half;
        Red[wav * 1024 + row * 32 + mn] = acc[r];
    }
    __syncthreads();

    if (tid < 256) {
        const int e0 = tid * 4, row = e0 >> 5, col = e0 & 31;
        float v[4];
        #pragma unroll
        for (int q = 0; q < 4; ++q) {
            float u = 0.f;
            #pragma unroll
            for (int w = 0; w < WAVES; ++w) u += Red[w * 1024 + e0 + q];
            if (HAS_BIAS) u += bias[n0 + col + q];
            if (RELU) u = lrelu(u);
            v[q] = u;
        }
        if (BF16_OUT) {
            uint2 o;
            o.x = pack2bf(v[0], v[1]); o.y = pack2bf(v[2], v[3]);
            *(uint2*)((unsigned short*)Cout + (size_t)(m0 + row) * N + n0 + col) = o;
        } else {
            *(float4*)((float*)Cout + (size_t)(m0 + row) * N + n0 + col) =
                make_float4(v[0], v[1], v[2], v[3]);
        }
    }
}

// ---------------------------------------------------------------------------
// Minibatch discrimination (round-0 verified code): Mt fp32 [640][512],
// block = (o, j-quarter, i-half): 1024 blocks x 128 threads.
// obH[ih][j][o] = sum_{i in half} exp(-L1) - (self ? 1 : 0)
// ---------------------------------------------------------------------------
__global__ __launch_bounds__(128)
void disc_kernel(const float* __restrict__ Mt, float* __restrict__ obH)
{
    const int o  = blockIdx.x >> 3;
    const int jq = (blockIdx.x >> 1) & 3;
    const int ih = blockIdx.x & 1;
    const int t  = threadIdx.x;
    const int j  = jq * 128 + t;
    const int i0 = ih * 256;
    __shared__ float L[256 * 8];
    const float* base = Mt + (size_t)o * 5 * 512;
    #pragma unroll
    for (int k = 0; k < KD_; ++k) {
        L[t * 8 + k]         = base[k * 512 + i0 + t];
        L[(t + 128) * 8 + k] = base[k * 512 + i0 + t + 128];
    }
    const float mj0 = base[0 * 512 + j], mj1 = base[1 * 512 + j],
                mj2 = base[2 * 512 + j], mj3 = base[3 * 512 + j],
                mj4 = base[4 * 512 + j];
    __syncthreads();

    float acc0 = 0.f, acc1 = 0.f;
    #pragma unroll 4
    for (int i = 0; i < 256; i += 2) {
        {
            const float4 a = *(const float4*)&L[i * 8];
            const float n = fabsf(a.x - mj0) + fabsf(a.y - mj1) + fabsf(a.z - mj2)
                          + fabsf(a.w - mj3) + fabsf(L[i * 8 + 4] - mj4);
            acc0 += __expf(-n);
        }
        {
            const float4 a = *(const float4*)&L[(i + 1) * 8];
            const float n = fabsf(a.x - mj0) + fabsf(a.y - mj1) + fabsf(a.z - mj2)
                          + fabsf(a.w - mj3) + fabsf(L[(i + 1) * 8 + 4] - mj4);
            acc1 += __expf(-n);
        }
    }
    const float self = ((j >> 8) == ih) ? 1.f : 0.f;
    obH[(size_t)ih * B_ * OUT_ + (size_t)j * OUT_ + o] = acc0 + acc1 - self;
}

// ---------------------------------------------------------------------------
// Fused GEMM3 + final dot: 16 blocks x 256 threads (round-0 verified,
// B operand now bf16 rows of W3t).
// ---------------------------------------------------------------------------
__global__ __launch_bounds__(256)
void gemm3_dot(const unsigned short* __restrict__ h2b,
               const float* __restrict__ obA, const float* __restrict__ obB,
               const unsigned short* __restrict__ W3t, const float* __restrict__ b3,
               const float* __restrict__ W4, const float* __restrict__ b4,
               float* __restrict__ out)
{
    __shared__ float Red[32 * 128];
    const int tid  = threadIdx.x;
    const int w    = tid >> 6;
    const int lane = tid & 63;
    const int half = lane >> 5;
    const int mn   = lane & 31;
    const int m0   = blockIdx.x * 32;
    const int n0   = w * 32;

    f32x16 acc;
    #pragma unroll
    for (int i = 0; i < 16; ++i) acc[i] = 0.f;

    #pragma unroll
    for (int s = 0; s < ZK_ / 16; ++s) {
        const int k = 16 * s + 8 * half;
        const bf16x8 af  = frag_concat(h2b, obA, obB, m0 + mn, k);
        const bf16x8 bfr = frag_bf16row(W3t, n0 + mn, ZK_, k);
        acc = __builtin_amdgcn_mfma_f32_32x32x16_bf16(af, bfr, acc, 0, 0, 0);
    }

    #pragma unroll
    for (int r = 0; r < 16; ++r) {
        const int row = (r & 3) + 8 * (r >> 2) + 4 * half;
        const int col = n0 + mn;
        Red[row * 128 + col] = lrelu(acc[r] + b3[col]);
    }
    __syncthreads();

    if (tid < 128) {
        const int row = tid >> 2, q = tid & 3;
        float a = 0.f;
        #pragma unroll
        for (int cc0 = 0; cc0 < 32; ++cc0) {
            const int cc = (cc0 + tid) & 31;       // rotation: 2-way LDS aliasing (free)
            a += Red[row * 128 + q * 32 + cc] * W4[q * 32 + cc];
        }
        a += __shfl_down(a, 2, 4);
        a += __shfl_down(a, 1, 4);
        if (q == 0) out[m0 + row] = a + b4[0];
    }
}

extern "C" void kernel_launch(void* const* d_in, const int* in_sizes, int n_in,
                              void* d_out, int out_size, void* d_ws, size_t ws_size,
                              hipStream_t stream) {
    const float* x  = (const float*)d_in[0];   // (512, 1024)
    const float* W1 = (const float*)d_in[1];   // (1024, 512)
    const float* b1 = (const float*)d_in[2];   // (512,)
    const float* W2 = (const float*)d_in[3];   // (512, 256)
    const float* b2 = (const float*)d_in[4];   // (256,)
    const float* T  = (const float*)d_in[5];   // (256, 640) flat
    const float* W3 = (const float*)d_in[6];   // (384, 128)
    const float* b3 = (const float*)d_in[7];   // (128,)
    const float* W4 = (const float*)d_in[8];   // (128, 1)
    const float* b4 = (const float*)d_in[9];   // (1,)
    float* out = (float*)d_out;                // (512,)

    char* ws = (char*)d_ws;
    float*          Mt  = (float*)(ws + 0);                  // 640*512*4   = 1310720
    float*          obH = (float*)(ws + 1310720);            // 2*512*128*4 =  524288
    unsigned short* h1b = (unsigned short*)(ws + 1835008);   // 512*512*2   =  524288
    unsigned short* h2b = (unsigned short*)(ws + 2359296);   // 512*256*2   =  262144
    unsigned short* xb  = (unsigned short*)(ws + 2621440);   // 512*1024*2  = 1048576
    unsigned short* W1t = (unsigned short*)(ws + 3670016);   // 512*1024*2  = 1048576
    unsigned short* W2t = (unsigned short*)(ws + 4718592);   // 256*512*2   =  262144
    unsigned short* Tt  = (unsigned short*)(ws + 4980736);   // 640*256*2   =  327680
    unsigned short* W3t = (unsigned short*)(ws + 5308416);   // 128*384*2   =   98304
    // total 5,406,720 bytes

    // 0) prep: bf16 transposes of W1/W2/T/W3 + bf16 convert of x
    prep_kernel<<<1104, 256, 0, stream>>>(x, W1, W2, T, W3, xb, W1t, W2t, Tt, W3t);

    // 1) h1 = lrelu(x @ W1 + b1)  (512x512, K=1024) -> bf16
    gemm_k<8, 128, true, true, true>
        <<<dim3(H1_ / 32, B_ / 32), 512, 0, stream>>>(
        xb, W1t, b1, h1b, H1_, F_, F_);

    // 2) h2 = lrelu(h1 @ W2 + b2) (512x256, K=512) -> bf16
    gemm_k<8, 64, true, true, true>
        <<<dim3(H2_ / 32, B_ / 32), 512, 0, stream>>>(
        h1b, W2t, b2, h2b, H2_, H1_, H1_);

    // 3) Mt = (h2 @ T)^T directly: A = Tt rows [640][256], B = h2b rows
    gemm_k<4, 64, false, false, false>
        <<<dim3(B_ / 32, NT_ / 32), 256, 0, stream>>>(
        Tt, h2b, nullptr, Mt, B_, H2_, H2_);

    // 4) minibatch discrimination -> obH (two i-half partials)
    disc_kernel<<<1024, 128, 0, stream>>>(Mt, obH);

    // 5) out = (lrelu(concat([h2, ob]) @ W3 + b3)) @ W4 + b4
    gemm3_dot<<<B_ / 32, 256, 0, stream>>>(
        h2b, obH, obH + B_ * OUT_, W3t, b3, W4, b4, out);
}